// Round 10
// baseline (262.318 us; speedup 1.0000x reference)
//
#include <hip/hip_runtime.h>

#define NB 2048
#define NULL_ATT (-4194304.0f)

typedef __attribute__((ext_vector_type(8))) _Float16 f16x8;
typedef __attribute__((ext_vector_type(2))) _Float16 h2;
typedef __attribute__((ext_vector_type(4))) float f32x4;

// Precomputed once per launch (module-scope device memory; no hipMalloc).
__device__ __align__(16) short g_wxf16[256 * 256];  // f16 of W1[:,256:512], [j][k]
__device__ float g_iq[NB * 256];                    // item@W1i^T + b1

// swizzled element offset into a [64][256] f16 LDS array (16B granules,
// XOR by (s&7): phase-2 A-frag ds_read_b128 is 2-way aliasing = free).
__device__ __forceinline__ int qoff(int s, int k) {
    int g = k >> 3;
    return s * 256 + (((g ^ (s & 7)) << 3) | (k & 7));
}

__device__ __forceinline__ f16x8 cvt8h(float4 a, float4 b) {
    f16x8 r;
    r[0] = (_Float16)a.x; r[1] = (_Float16)a.y; r[2] = (_Float16)a.z; r[3] = (_Float16)a.w;
    r[4] = (_Float16)b.x; r[5] = (_Float16)b.y; r[6] = (_Float16)b.z; r[7] = (_Float16)b.w;
    return r;
}

// Chunked stage: 4 kc (8 x float4 = 32 raw VGPRs) per batch, to fit a
// 64-VGPR budget. Two batches serialize one extra latency; TLP covers it.
__device__ __forceinline__ void stage4(const float* __restrict__ p, f16x8* dst) {
    float4 r[4][2];
    #pragma unroll
    for (int kc = 0; kc < 4; ++kc) {
        r[kc][0] = *(const float4*)(p + kc * 32);
        r[kc][1] = *(const float4*)(p + kc * 32 + 4);
    }
    #pragma unroll
    for (int kc = 0; kc < 4; ++kc) dst[kc] = cvt8h(r[kc][0], r[kc][1]);
}
__device__ __forceinline__ void stage8c(const float* __restrict__ p, f16x8 dst[8]) {
    stage4(p, dst);
    stage4(p + 128, dst + 4);
}

// Merged prep: blocks 0..255 convert W1x to f16; blocks 256..383 compute
// iq[m][j] = item[m,:] @ W1[j,:256] + b1[j] in 16-row tiles (f16 MFMA).
__global__ __launch_bounds__(256, 4) void prep(const float* __restrict__ item_emb,
                                               const float* __restrict__ W1,
                                               const float* __restrict__ b1) {
    if (blockIdx.x < 256) {
        int j = blockIdx.x, k = threadIdx.x;
        g_wxf16[j * 256 + k] =
            __builtin_bit_cast(short, (_Float16)W1[(size_t)j * 512 + 256 + k]);
        return;
    }
    const int m0 = (blockIdx.x - 256) * 16;
    const int t = threadIdx.x, wave = t >> 6, lane = t & 63;
    const int lr = lane & 15, lo8 = lane >> 4;
    const int jb = wave * 64;

    f16x8 afr[8];
    stage8c(item_emb + (size_t)(m0 + lr) * 256 + lo8 * 8, afr);

    f32x4 acc[4];
    #pragma unroll
    for (int jt = 0; jt < 4; ++jt) acc[jt] = f32x4{0.f, 0.f, 0.f, 0.f};
    #pragma unroll
    for (int kc = 0; kc < 8; ++kc) {
        #pragma unroll
        for (int jt = 0; jt < 4; ++jt) {
            const float* wp = W1 + (size_t)(jb + jt * 16 + lr) * 512 + kc * 32 + lo8 * 8;
            f16x8 bfr = cvt8h(*(const float4*)wp, *(const float4*)(wp + 4));
            acc[jt] = __builtin_amdgcn_mfma_f32_16x16x32_f16(afr[kc], bfr, acc[jt], 0, 0, 0);
        }
    }
    #pragma unroll
    for (int jt = 0; jt < 4; ++jt) {
        float bv = b1[jb + jt * 16 + lr];
        #pragma unroll
        for (int i = 0; i < 4; ++i)
            g_iq[(size_t)(m0 + lo8 * 4 + i) * 256 + jb + jt * 16 + lr] = acc[jt][i] + bv;
    }
}

// in-place logical view of parr[8] (f16x8) as 32 h2 values
#define AA_GET(i) (h2{parr[(i) >> 2][(((i) & 3) << 1)], parr[(i) >> 2][(((i) & 3) << 1) | 1]})
#define AA_SET(i, v) { parr[(i) >> 2][(((i) & 3) << 1)] = (v)[0]; \
                       parr[(i) >> 2][(((i) & 3) << 1) | 1] = (v)[1]; }

__global__ __launch_bounds__(512, 8) void coatt_main(
    const float* __restrict__ x_session,   // [B,64,256]
    const int*   __restrict__ session_len, // [B]
    const float* __restrict__ user_hist,   // [B,256,256]
    const int*   __restrict__ hist_len,    // [B]
    float* __restrict__ out)               // [B*256 rep | B*256 score]
{
    const int b = blockIdx.x;
    const int t = threadIdx.x;
    const int wave = t >> 6;        // 0..7
    const int lane = t & 63;
    const int lr  = lane & 15;
    const int lo8 = lane >> 4;
    const int sl = session_len[b];
    const int hl = hist_len[b];

    __shared__ __align__(16) short qf[64 * 256];   // 32 KB f16 query tile
    __shared__ float sMax[256];
    __shared__ float red2[16];                     // [0..7]=M_w, [8..15]=D_w
    __shared__ __align__(8) h2 Vp[8][128];         // per-wave V partials (f16 pairs)

    if (t < 256) sMax[t] = NULL_ATT;
    const int nst = (sl > 0) ? min(4, (sl + 15) >> 4) : 0;

    // ---- Phase 1 (f16 MFMA): wave (st = w&3, jh = w>>2) owns a 16s x 128j tile ----
    if ((wave & 3) < nst) {
        const int st = wave & 3;
        const int jh = wave >> 2;
        float iqv[2][4];
        #pragma unroll
        for (int jc2 = 0; jc2 < 2; ++jc2) {
            const int jc = jh * 2 + jc2;
            #pragma unroll
            for (int jt = 0; jt < 4; ++jt)
                iqv[jc2][jt] = g_iq[(size_t)b * 256 + jc * 64 + jt * 16 + lr];
        }
        f16x8 afr[8];
        stage8c(x_session + ((size_t)b * 64 + st * 16 + lr) * 256 + lo8 * 8, afr);

        #pragma unroll
        for (int jc2 = 0; jc2 < 2; ++jc2) {
            const int jc = jh * 2 + jc2;
            f32x4 acc[4];
            #pragma unroll
            for (int jt = 0; jt < 4; ++jt)
                acc[jt] = f32x4{iqv[jc2][jt], iqv[jc2][jt], iqv[jc2][jt], iqv[jc2][jt]};
            #pragma unroll
            for (int kc = 0; kc < 8; ++kc) {
                #pragma unroll
                for (int jt = 0; jt < 4; ++jt) {
                    f16x8 bfr2 = *(const f16x8*)&g_wxf16[(jc * 64 + jt * 16 + lr) * 256 + kc * 32 + lo8 * 8];
                    acc[jt] = __builtin_amdgcn_mfma_f32_16x16x32_f16(afr[kc], bfr2, acc[jt], 0, 0, 0);
                }
            }
            #pragma unroll
            for (int jt = 0; jt < 4; ++jt) {
                int j = jc * 64 + jt * 16 + lr;
                #pragma unroll
                for (int i = 0; i < 4; ++i)
                    qf[qoff(st * 16 + lo8 * 4 + i, j)] =
                        __builtin_bit_cast(short, (_Float16)acc[jt][i]);
            }
        }
    }

    // ---- pre-stage slot-0 hist rows (independent of q; hides under barrier) ----
    const int nht = (hl + 15) >> 4;
    const bool p2 = (nst > 0 && hl > 0);
    const float* hB = user_hist + (size_t)b * 256 * 256;
    f16x8 bcur[8];
    if (p2 && wave < nht)
        stage8c(hB + (size_t)(wave * 16 + lr) * 256 + lo8 * 8, bcur);
    __syncthreads();

    // ---- Phase 2 (f16 MFMA): scores + online PV accum in h-row layout ----
    float Mrun = -3.0e38f;
    float Drun = 0.0f;
    f16x8 parr[8];
    #pragma unroll
    for (int kc = 0; kc < 8; ++kc) parr[kc] = f16x8{0, 0, 0, 0, 0, 0, 0, 0};

    if (p2) {
        auto slot_body = [&](int ht) {
            f32x4 acc[4];
            #pragma unroll
            for (int st = 0; st < 4; ++st) acc[st] = f32x4{0.f, 0.f, 0.f, 0.f};
            #pragma unroll
            for (int kc = 0; kc < 8; ++kc) {
                #pragma unroll
                for (int st = 0; st < 4; ++st) {
                    if (st < nst) {
                        f16x8 a = *(const f16x8*)&qf[qoff(st * 16 + lr, kc * 32 + lo8 * 8)];
                        acc[st] = __builtin_amdgcn_mfma_f32_16x16x32_f16(a, bcur[kc], acc[st], 0, 0, 0);
                    }
                }
            }
            float m = NULL_ATT;
            #pragma unroll
            for (int st = 0; st < 4; ++st) {
                if (st < nst) {
                    #pragma unroll
                    for (int i = 0; i < 4; ++i) {
                        int s = st * 16 + lo8 * 4 + i;
                        if (s < sl) m = fmaxf(m, acc[st][i]);
                    }
                }
            }
            m = fmaxf(m, __shfl_xor(m, 16, 64));
            m = fmaxf(m, __shfl_xor(m, 32, 64));
            const int h = ht * 16 + lr;
            if (lane < 16 && h < hl) sMax[h] = m;

            float sh = (h < hl) ? m : NULL_ATT;
            float mt = sh;
            mt = fmaxf(mt, __shfl_xor(mt, 1, 64));
            mt = fmaxf(mt, __shfl_xor(mt, 2, 64));
            mt = fmaxf(mt, __shfl_xor(mt, 4, 64));
            mt = fmaxf(mt, __shfl_xor(mt, 8, 64));   // tile max, wave-uniform
            if (mt > Mrun) {                          // wave-uniform branch
                float scl = __expf(Mrun - mt);        // 0 on first tile
                Drun *= scl;
                const _Float16 s16 = (_Float16)scl;
                f16x8 s8 = {s16, s16, s16, s16, s16, s16, s16, s16};
                #pragma unroll
                for (int kc = 0; kc < 8; ++kc) parr[kc] *= s8;
                Mrun = mt;
            }
            float eh = __expf(sh - Mrun);             // 0 for invalid h
            Drun += eh;
            const _Float16 e16 = (_Float16)eh;
            f16x8 e8 = {e16, e16, e16, e16, e16, e16, e16, e16};
            #pragma unroll
            for (int kc = 0; kc < 8; ++kc) parr[kc] = bcur[kc] * e8 + parr[kc];
        };

        if (wave < nht) slot_body(wave);              // pre-staged
        const int ht1 = wave + 8;
        if (ht1 < nht) {                              // only when hl > 128
            stage8c(hB + (size_t)(ht1 * 16 + lr) * 256 + lo8 * 8, bcur);
            slot_body(ht1);
        }

        // ---- ONE butterfly transpose-reduce over the 16-lane lr group ----
        #pragma unroll
        for (int sb = 0; sb < 4; ++sb) {
            const int bmask = 8 >> sb;
            const int half = 16 >> sb;
            const bool hi = (lr & bmask) != 0;
            #pragma unroll
            for (int i = 0; i < (16 >> sb); ++i) {
                h2 a0 = AA_GET(i);
                h2 a1 = AA_GET(i + half);
                h2 keep = hi ? a1 : a0;
                h2 send = hi ? a0 : a1;
                int ru = __shfl_xor(__builtin_bit_cast(int, send), bmask, 64);
                h2 res = keep + __builtin_bit_cast(h2, ru);
                AA_SET(i, res);
            }
        }
        h2 f0 = AA_GET(0), f1 = AA_GET(1);

        float Dl = Drun;
        Dl += __shfl_xor(Dl, 1, 64);
        Dl += __shfl_xor(Dl, 2, 64);
        Dl += __shfl_xor(Dl, 4, 64);
        Dl += __shfl_xor(Dl, 8, 64);
        if (lane == 0) { red2[wave] = Mrun; red2[8 + wave] = Dl; }
        const int col0 = (lr >> 1) * 32 + lo8 * 8 + (lr & 1) * 4;
        Vp[wave][col0 >> 1] = f0;
        Vp[wave][(col0 >> 1) + 1] = f1;
    } else {
        // ---- fallback (~2% of blocks): uniform weights; fold into combine ----
        f32x4 a4 = {0.f, 0.f, 0.f, 0.f};
        const float* hc = hB + lane * 4;
        for (int h = wave; h < 256; h += 32) {
            float4 v0 = *(const float4*)(hc + (size_t)(h)      * 256);
            float4 v1 = *(const float4*)(hc + (size_t)(h + 8)  * 256);
            float4 v2 = *(const float4*)(hc + (size_t)(h + 16) * 256);
            float4 v3 = *(const float4*)(hc + (size_t)(h + 24) * 256);
            a4[0] += (v0.x + v1.x) + (v2.x + v3.x);
            a4[1] += (v0.y + v1.y) + (v2.y + v3.y);
            a4[2] += (v0.z + v1.z) + (v2.z + v3.z);
            a4[3] += (v0.w + v1.w) + (v2.w + v3.w);
        }
        Vp[wave][lane * 2]     = h2{(_Float16)a4[0], (_Float16)a4[1]};
        Vp[wave][lane * 2 + 1] = h2{(_Float16)a4[2], (_Float16)a4[3]};
        if (lane == 0) { red2[wave] = 0.f; red2[8 + wave] = 32.f; }
    }
    __syncthreads();

    // ---- outputs: score + combined rep (common path) ----
    if (t < 256) {
        out[(size_t)NB * 256 + (size_t)b * 256 + t] = sMax[t];
        float Ms = red2[0];
        #pragma unroll
        for (int w = 1; w < 8; ++w) Ms = fmaxf(Ms, red2[w]);
        float num = 0.f, den = 0.f;
        #pragma unroll
        for (int w = 0; w < 8; ++w) {
            float ww = __expf(red2[w] - Ms);
            den += ww * red2[8 + w];
            h2 v = Vp[w][t >> 1];
            num += ww * (float)v[t & 1];
        }
        out[(size_t)b * 256 + t] = num / den;
    }
}

extern "C" void kernel_launch(void* const* d_in, const int* in_sizes, int n_in,
                              void* d_out, int out_size, void* d_ws, size_t ws_size,
                              hipStream_t stream) {
    const float* item_emb    = (const float*)d_in[0];
    const float* x_session   = (const float*)d_in[1];
    const int*   session_len = (const int*)d_in[2];
    const float* user_hist   = (const float*)d_in[3];
    const int*   hist_len    = (const int*)d_in[4];
    const float* W1          = (const float*)d_in[5];
    const float* b1          = (const float*)d_in[6];
    float* out = (float*)d_out;

    prep<<<384, 256, 0, stream>>>(item_emb, W1, b1);
    coatt_main<<<NB, 512, 0, stream>>>(x_session, session_len, user_hist, hist_len, out);
}

// Round 11
// 163.805 us; speedup vs baseline: 1.6014x; 1.6014x over previous
//
#include <hip/hip_runtime.h>

#define NB 2048
#define NULL_ATT (-4194304.0f)

typedef __attribute__((ext_vector_type(8))) _Float16 f16x8;
typedef __attribute__((ext_vector_type(2))) _Float16 h2;
typedef __attribute__((ext_vector_type(4))) float f32x4;

// Precomputed once per launch (module-scope device memory; no hipMalloc).
__device__ __align__(16) short g_wxf16[256 * 256];  // f16 of W1[:,256:512], [j][k]
__device__ float g_iq[NB * 256];                    // item@W1i^T + b1

// swizzled element offset into a [64][256] f16 LDS array (16B granules,
// XOR by (s&7): phase-2 A-frag ds_read_b128 is 2-way aliasing = free).
__device__ __forceinline__ int qoff(int s, int k) {
    int g = k >> 3;
    return s * 256 + (((g ^ (s & 7)) << 3) | (k & 7));
}

__device__ __forceinline__ f16x8 cvt8h(float4 a, float4 b) {
    f16x8 r;
    r[0] = (_Float16)a.x; r[1] = (_Float16)a.y; r[2] = (_Float16)a.z; r[3] = (_Float16)a.w;
    r[4] = (_Float16)b.x; r[5] = (_Float16)b.y; r[6] = (_Float16)b.z; r[7] = (_Float16)b.w;
    return r;
}

// split stage: issue 16 dwordx4 loads (raw regs) / convert later.
// FIFO vmcnt: converting an EARLIER-issued batch only waits on that batch.
__device__ __forceinline__ void issue16(const float* __restrict__ p, float4 r[8][2]) {
    #pragma unroll
    for (int kc = 0; kc < 8; ++kc) {
        r[kc][0] = *(const float4*)(p + kc * 32);
        r[kc][1] = *(const float4*)(p + kc * 32 + 4);
    }
}
__device__ __forceinline__ void conv16(const float4 r[8][2], f16x8 dst[8]) {
    #pragma unroll
    for (int kc = 0; kc < 8; ++kc) dst[kc] = cvt8h(r[kc][0], r[kc][1]);
}

// Merged prep: blocks 0..255 convert W1x to f16; blocks 256..383 compute
// iq[m][j] = item[m,:] @ W1[j,:256] + b1[j] in 16-row tiles (f16 MFMA).
__global__ __launch_bounds__(256, 2) void prep(const float* __restrict__ item_emb,
                                               const float* __restrict__ W1,
                                               const float* __restrict__ b1) {
    if (blockIdx.x < 256) {
        int j = blockIdx.x, k = threadIdx.x;
        g_wxf16[j * 256 + k] =
            __builtin_bit_cast(short, (_Float16)W1[(size_t)j * 512 + 256 + k]);
        return;
    }
    const int m0 = (blockIdx.x - 256) * 16;
    const int t = threadIdx.x, wave = t >> 6, lane = t & 63;
    const int lr = lane & 15, lo8 = lane >> 4;
    const int jb = wave * 64;

    float4 ir[8][2];
    issue16(item_emb + (size_t)(m0 + lr) * 256 + lo8 * 8, ir);
    f16x8 afr[8];
    conv16(ir, afr);

    f32x4 acc[4];
    #pragma unroll
    for (int jt = 0; jt < 4; ++jt) acc[jt] = f32x4{0.f, 0.f, 0.f, 0.f};
    #pragma unroll
    for (int kc = 0; kc < 8; ++kc) {
        #pragma unroll
        for (int jt = 0; jt < 4; ++jt) {
            const float* wp = W1 + (size_t)(jb + jt * 16 + lr) * 512 + kc * 32 + lo8 * 8;
            f16x8 bfr = cvt8h(*(const float4*)wp, *(const float4*)(wp + 4));
            acc[jt] = __builtin_amdgcn_mfma_f32_16x16x32_f16(afr[kc], bfr, acc[jt], 0, 0, 0);
        }
    }
    #pragma unroll
    for (int jt = 0; jt < 4; ++jt) {
        float bv = b1[jb + jt * 16 + lr];
        #pragma unroll
        for (int i = 0; i < 4; ++i)
            g_iq[(size_t)(m0 + lo8 * 4 + i) * 256 + jb + jt * 16 + lr] = acc[jt][i] + bv;
    }
}

// in-place logical view of parr[8] (f16x8) as 32 h2 values
#define AA_GET(i) (h2{parr[(i) >> 2][(((i) & 3) << 1)], parr[(i) >> 2][(((i) & 3) << 1) | 1]})
#define AA_SET(i, v) { parr[(i) >> 2][(((i) & 3) << 1)] = (v)[0]; \
                       parr[(i) >> 2][(((i) & 3) << 1) | 1] = (v)[1]; }

__global__ __launch_bounds__(256, 2) void coatt_main(
    const float* __restrict__ x_session,   // [B,64,256]
    const int*   __restrict__ session_len, // [B]
    const float* __restrict__ user_hist,   // [B,256,256]
    const int*   __restrict__ hist_len,    // [B]
    float* __restrict__ out)               // [B*256 rep | B*256 score]
{
    const int b = blockIdx.x;
    const int t = threadIdx.x;
    const int wave = t >> 6;
    const int lane = t & 63;
    const int lr  = lane & 15;
    const int lo8 = lane >> 4;
    const int sl = session_len[b];
    const int hl = hist_len[b];

    __shared__ __align__(16) short qf[64 * 256];   // 32 KB f16 query tile
    __shared__ float sMax[256];
    __shared__ float red2[8];                      // [0..3]=M_w, [4..7]=D_w
    __shared__ __align__(16) float Vp[4][256];     // per-wave V partials

    sMax[t] = NULL_ATT;
    const int nst = (sl > 0) ? min(4, (sl + 15) >> 4) : 0;
    const int nht = (hl + 15) >> 4;
    const bool p2 = (nst > 0 && hl > 0);
    const float* hB = user_hist + (size_t)b * 256 * 256;
    const bool havePre = p2 && (wave < nht);

    float4 hraw[8][2];
    f16x8 bcur[8];

    // ---- Phase 1 (f16 MFMA): wave w owns s-tile w; slot-0 hist loads ride along ----
    if (wave < nst) {
        const int st = wave;
        float4 xraw[8][2];
        issue16(x_session + ((size_t)b * 64 + st * 16 + lr) * 256 + lo8 * 8, xraw);
        if (havePre)   // issued AFTER x: x-conversion waits only on x (vmcnt FIFO)
            issue16(hB + (size_t)(wave * 16 + lr) * 256 + lo8 * 8, hraw);
        f16x8 afr[8];
        conv16(xraw, afr);

        #pragma unroll
        for (int jc = 0; jc < 4; ++jc) {
            f32x4 acc[4];
            #pragma unroll
            for (int jt = 0; jt < 4; ++jt) {
                float v = g_iq[(size_t)b * 256 + jc * 64 + jt * 16 + lr];
                acc[jt] = f32x4{v, v, v, v};
            }
            #pragma unroll
            for (int kc = 0; kc < 8; ++kc) {
                #pragma unroll
                for (int jt = 0; jt < 4; ++jt) {
                    f16x8 bfr2 = *(const f16x8*)&g_wxf16[(jc * 64 + jt * 16 + lr) * 256 + kc * 32 + lo8 * 8];
                    acc[jt] = __builtin_amdgcn_mfma_f32_16x16x32_f16(afr[kc], bfr2, acc[jt], 0, 0, 0);
                }
            }
            #pragma unroll
            for (int jt = 0; jt < 4; ++jt) {
                int j = jc * 64 + jt * 16 + lr;
                #pragma unroll
                for (int i = 0; i < 4; ++i)
                    qf[qoff(st * 16 + lo8 * 4 + i, j)] =
                        __builtin_bit_cast(short, (_Float16)acc[jt][i]);
            }
        }
    } else if (havePre) {
        issue16(hB + (size_t)(wave * 16 + lr) * 256 + lo8 * 8, hraw);
    }
    if (havePre) conv16(hraw, bcur);   // latency hidden under phase-1 compute
    __syncthreads();

    // ---- Phase 2 (f16 MFMA): scores + online PV accum; raw prefetch of next slot ----
    float Mrun = -3.0e38f;
    float Drun = 0.0f;
    f16x8 parr[8];
    #pragma unroll
    for (int kc = 0; kc < 8; ++kc) parr[kc] = f16x8{0, 0, 0, 0, 0, 0, 0, 0};

    if (p2) {
        for (int slot = 0; slot < 4; ++slot) {
            const int ht = wave + slot * 4;
            if (ht >= nht) break;
            const int htn = ht + 4;
            const bool pre = (htn < nht);
            if (pre)   // issue next slot's raw loads; convert after this slot's compute
                issue16(hB + (size_t)(htn * 16 + lr) * 256 + lo8 * 8, hraw);

            f32x4 acc[4];
            #pragma unroll
            for (int st = 0; st < 4; ++st) acc[st] = f32x4{0.f, 0.f, 0.f, 0.f};
            #pragma unroll
            for (int kc = 0; kc < 8; ++kc) {
                #pragma unroll
                for (int st = 0; st < 4; ++st) {
                    if (st < nst) {
                        f16x8 a = *(const f16x8*)&qf[qoff(st * 16 + lr, kc * 32 + lo8 * 8)];
                        acc[st] = __builtin_amdgcn_mfma_f32_16x16x32_f16(a, bcur[kc], acc[st], 0, 0, 0);
                    }
                }
            }
            // masked max over s -> score for h = ht*16+lr (in all lanes)
            float m = NULL_ATT;
            #pragma unroll
            for (int st = 0; st < 4; ++st) {
                if (st < nst) {
                    #pragma unroll
                    for (int i = 0; i < 4; ++i) {
                        int s = st * 16 + lo8 * 4 + i;
                        if (s < sl) m = fmaxf(m, acc[st][i]);
                    }
                }
            }
            m = fmaxf(m, __shfl_xor(m, 16, 64));
            m = fmaxf(m, __shfl_xor(m, 32, 64));
            const int h = ht * 16 + lr;
            if (lane < 16 && h < hl) sMax[h] = m;

            // ---- online softmax update (M wave-uniform) ----
            float sh = (h < hl) ? m : NULL_ATT;
            float mt = sh;
            mt = fmaxf(mt, __shfl_xor(mt, 1, 64));
            mt = fmaxf(mt, __shfl_xor(mt, 2, 64));
            mt = fmaxf(mt, __shfl_xor(mt, 4, 64));
            mt = fmaxf(mt, __shfl_xor(mt, 8, 64));   // tile max, wave-uniform
            if (mt > Mrun) {                          // wave-uniform branch
                float scl = __expf(Mrun - mt);        // 0 on first tile
                Drun *= scl;
                const _Float16 s16 = (_Float16)scl;
                f16x8 s8 = {s16, s16, s16, s16, s16, s16, s16, s16};
                #pragma unroll
                for (int kc = 0; kc < 8; ++kc) parr[kc] *= s8;
                Mrun = mt;
            }
            float eh = __expf(sh - Mrun);             // 0 for invalid h
            Drun += eh;

            // ---- PV accumulate in h-row layout: parr += e * bcur (pk_fma) ----
            {
                const _Float16 e16 = (_Float16)eh;
                f16x8 e8 = {e16, e16, e16, e16, e16, e16, e16, e16};
                #pragma unroll
                for (int kc = 0; kc < 8; ++kc) parr[kc] = bcur[kc] * e8 + parr[kc];
            }
            if (pre) conv16(hraw, bcur);   // loads have had the whole slot to land
        }

        // ---- ONE butterfly transpose-reduce over the 16-lane lr group ----
        #pragma unroll
        for (int sb = 0; sb < 4; ++sb) {
            const int bmask = 8 >> sb;
            const int half = 16 >> sb;
            const bool hi = (lr & bmask) != 0;
            #pragma unroll
            for (int i = 0; i < (16 >> sb); ++i) {
                h2 a0 = AA_GET(i);
                h2 a1 = AA_GET(i + half);
                h2 keep = hi ? a1 : a0;
                h2 send = hi ? a0 : a1;
                int ru = __shfl_xor(__builtin_bit_cast(int, send), bmask, 64);
                h2 res = keep + __builtin_bit_cast(h2, ru);
                AA_SET(i, res);
            }
        }
        // lane now owns 4 consecutive cols at col0 = (lr>>1)*32 + lo8*8 + (lr&1)*4
        h2 f0 = AA_GET(0), f1 = AA_GET(1);

        // per-wave partials: D (sum over 16 lr lanes), M, V columns
        float Dl = Drun;
        Dl += __shfl_xor(Dl, 1, 64);
        Dl += __shfl_xor(Dl, 2, 64);
        Dl += __shfl_xor(Dl, 4, 64);
        Dl += __shfl_xor(Dl, 8, 64);
        if (lane == 0) { red2[wave] = Mrun; red2[4 + wave] = Dl; }
        const int col0 = (lr >> 1) * 32 + lo8 * 8 + (lr & 1) * 4;
        *(float4*)&Vp[wave][col0] =
            float4{(float)f0[0], (float)f0[1], (float)f1[0], (float)f1[1]};
    }
    __syncthreads();

    // ---- score output (always) ----
    float sc = sMax[t];
    out[(size_t)NB * 256 + (size_t)b * 256 + t] = sc;

    if (p2) {
        // ---- combine 4 waves' online states; rep[t] ----
        float M0 = red2[0], M1 = red2[1], M2 = red2[2], M3 = red2[3];
        float Ms = fmaxf(fmaxf(M0, M1), fmaxf(M2, M3));
        float w0 = __expf(M0 - Ms), w1 = __expf(M1 - Ms);
        float w2 = __expf(M2 - Ms), w3 = __expf(M3 - Ms);
        float denom = w0 * red2[4] + w1 * red2[5] + w2 * red2[6] + w3 * red2[7];
        float num = w0 * Vp[0][t] + w1 * Vp[1][t] + w2 * Vp[2][t] + w3 * Vp[3][t];
        out[(size_t)b * 256 + t] = num / denom;
    } else {
        // ---- fallback (~2% of blocks): all scores NULL -> uniform 1/256 ----
        f32x4 a4 = {0.f, 0.f, 0.f, 0.f};
        const float* hc = hB + lane * 4;
        for (int h = wave; h < 256; h += 16) {
            float4 v0 = *(const float4*)(hc + (size_t)(h)      * 256);
            float4 v1 = *(const float4*)(hc + (size_t)(h + 4)  * 256);
            float4 v2 = *(const float4*)(hc + (size_t)(h + 8)  * 256);
            float4 v3 = *(const float4*)(hc + (size_t)(h + 12) * 256);
            a4[0] += (v0.x + v1.x) + (v2.x + v3.x);
            a4[1] += (v0.y + v1.y) + (v2.y + v3.y);
            a4[2] += (v0.z + v1.z) + (v2.z + v3.z);
            a4[3] += (v0.w + v1.w) + (v2.w + v3.w);
        }
        *(float4*)&Vp[wave][lane * 4] = float4{a4[0], a4[1], a4[2], a4[3]};
        __syncthreads();
        out[(size_t)b * 256 + t] =
            ((Vp[0][t] + Vp[1][t]) + (Vp[2][t] + Vp[3][t])) * (1.0f / 256.0f);
    }
}

extern "C" void kernel_launch(void* const* d_in, const int* in_sizes, int n_in,
                              void* d_out, int out_size, void* d_ws, size_t ws_size,
                              hipStream_t stream) {
    const float* item_emb    = (const float*)d_in[0];
    const float* x_session   = (const float*)d_in[1];
    const int*   session_len = (const int*)d_in[2];
    const float* user_hist   = (const float*)d_in[3];
    const int*   hist_len    = (const int*)d_in[4];
    const float* W1          = (const float*)d_in[5];
    const float* b1          = (const float*)d_in[6];
    float* out = (float*)d_out;

    prep<<<384, 256, 0, stream>>>(item_emb, W1, b1);
    coatt_main<<<NB, 256, 0, stream>>>(x_session, session_len, user_hist, hist_len, out);
}